// Round 8
// baseline (391.544 us; speedup 1.0000x reference)
//
#include <hip/hip_runtime.h>
#include <hip/hip_bf16.h>
#include <math.h>

typedef unsigned long long ull;

// Problem constants
#define BB_ 16          // images
#define PP_ 1000        // proposals per image
#define CC_ 91          // classes incl background
#define FF_ 1024        // feature dim
#define DETS_ 100
#define CAP_ 2048       // candidate capacity per image (measured ~320)
#define CAND_MAX (BB_ * CAP_)
#define SURV_CAP 2048   // NMS-survivor capacity per image
#define CLS_CAP 256     // per-(image,class) candidate capacity
#define IMG_W 800.0f
#define IMG_H 800.0f
#define OFF_ 802.0f     // max(H,W)+2
#define SCORE_TH 0.05f
#define NMS_TH 0.5f
#define MIN_SZ 0.01f
#define BBOX_CLIP_D 4.135166556742356   // log(1000/16)

// ---------------------------------------------------------------------------
// Kernel 0: Wc (fp32 [1024][91]) -> Wcd (fp64 [1024][96], zero-padded cols).
// Exact conversion; enables convert-free B path in the GEMM.
// ---------------------------------------------------------------------------
__global__ __launch_bounds__(256) void wc_to_double(
    const float* __restrict__ Wc, double* __restrict__ Wcd)
{
    const int idx = blockIdx.x * 256 + threadIdx.x;
    if (idx >= FF_ * 96) return;
    const int k = idx / 96, c = idx - k * 96;
    Wcd[idx] = (c < CC_) ? (double)Wc[(size_t)k * CC_ + c] : 0.0;
}

// ---------------------------------------------------------------------------
// Kernel 1: logits GEMM, FP64 accumulation. 16 rows x 96 cols per block,
// 128 threads (2 waves), 1000 blocks. B staged as DOUBLE from pre-converted
// Wcd (no converts in hot loop); A staged as float (2 cvt/k-step).
// Per-output K-accumulation strictly sequential -> same bits as R6/R7 pass.
// ---------------------------------------------------------------------------
__global__ __launch_bounds__(128) void logits_cand(
    const float* __restrict__ A, const double* __restrict__ Wcd,
    const float* __restrict__ bc,
    float* __restrict__ cs, int* __restrict__ clab,
    int* __restrict__ corig, int* __restrict__ cpidx,
    int* __restrict__ cnt)
{
    __shared__ union __align__(16) SM {
        struct { double Bd[16][98]; float Af[16][18]; } t;   // 13.7 KB
        float Ssc[16][97];
    } sm;

    const int tid = threadIdx.x;
    const int row0 = blockIdx.x * 16;

    // compute mapping: 8 row-groups x 16 col-groups, 2 rows x 6 cols each
    const int ty2 = (tid >> 4) * 2;      // 0,2,..,14
    const int tx6 = (tid & 15) * 6;      // 0,6,..,90

    // A staging: 16 rows x 16 k, float2 per thread
    const int ar  = tid >> 3;            // 0..15
    const int ak2 = (tid & 7) * 2;       // 0,2,..,14
    // B staging: 16 k x 96 cols, 6 double2 per thread
    const int bk  = tid >> 3;            // 0..15
    const int bco = (tid & 7) * 12;      // 0,12,..,84

    double acc[2][6];
#pragma unroll
    for (int i = 0; i < 2; ++i)
#pragma unroll
        for (int j = 0; j < 6; ++j) acc[i][j] = 0.0;

    // prologue prefetch (k0 = 0)
    float2 avP = *reinterpret_cast<const float2*>(
        A + (size_t)(row0 + ar) * FF_ + ak2);
    double2 bvP[6];
#pragma unroll
    for (int j = 0; j < 6; ++j)
        bvP[j] = *reinterpret_cast<const double2*>(
            Wcd + (size_t)bk * 96 + bco + 2 * j);

    for (int k0 = 0; k0 < FF_; k0 += 16) {
        // stage current tile
        sm.t.Af[ak2 + 0][ar] = avP.x;
        sm.t.Af[ak2 + 1][ar] = avP.y;
#pragma unroll
        for (int j = 0; j < 6; ++j)
            *reinterpret_cast<double2*>(&sm.t.Bd[bk][bco + 2 * j]) = bvP[j];

        // prefetch next tile
        const int kn = k0 + 16;
        if (kn < FF_) {
            avP = *reinterpret_cast<const float2*>(
                A + (size_t)(row0 + ar) * FF_ + kn + ak2);
#pragma unroll
            for (int j = 0; j < 6; ++j)
                bvP[j] = *reinterpret_cast<const double2*>(
                    Wcd + (size_t)(kn + bk) * 96 + bco + 2 * j);
        }
        __syncthreads();

#pragma unroll
        for (int k = 0; k < 16; ++k) {
            const float2 af = *reinterpret_cast<const float2*>(&sm.t.Af[k][ty2]);
            const double a0 = (double)af.x, a1 = (double)af.y;
            const double2 b01 = *reinterpret_cast<const double2*>(&sm.t.Bd[k][tx6 + 0]);
            const double2 b23 = *reinterpret_cast<const double2*>(&sm.t.Bd[k][tx6 + 2]);
            const double2 b45 = *reinterpret_cast<const double2*>(&sm.t.Bd[k][tx6 + 4]);
            acc[0][0] += a0 * b01.x; acc[0][1] += a0 * b01.y;
            acc[0][2] += a0 * b23.x; acc[0][3] += a0 * b23.y;
            acc[0][4] += a0 * b45.x; acc[0][5] += a0 * b45.y;
            acc[1][0] += a1 * b01.x; acc[1][1] += a1 * b01.y;
            acc[1][2] += a1 * b23.x; acc[1][3] += a1 * b23.y;
            acc[1][4] += a1 * b45.x; acc[1][5] += a1 * b45.y;
        }
        __syncthreads();
    }

    // fp32 logits (+bias) into LDS (tiles dead past the barrier above)
#pragma unroll
    for (int i = 0; i < 2; ++i)
#pragma unroll
        for (int j = 0; j < 6; ++j) {
            const int c = tx6 + j;
            if (c < CC_) {
                const float lf = (float)acc[i][j];
                sm.Ssc[ty2 + i][c] = __fadd_rn(lf, bc[c]);
            }
        }
    __syncthreads();

    // per-row fp64 softmax + threshold; threads 0..15 (one row each)
    if (tid < 16) {
        const int p = row0 + tid;
        const int b = p / PP_;
        const int pi = p - b * PP_;

        float m = sm.Ssc[tid][0];
        for (int c = 1; c < CC_; ++c) m = fmaxf(m, sm.Ssc[tid][c]);
        double denom = 0.0;
        for (int c = 0; c < CC_; ++c)
            denom += exp((double)sm.Ssc[tid][c] - (double)m);

        for (int c = 1; c < CC_; ++c) {
            const double sd = exp((double)sm.Ssc[tid][c] - (double)m) / denom;
            const float score = (float)sd;
            if (score > SCORE_TH) {
                const int pos = atomicAdd(&cnt[b], 1);
                if (pos < CAP_) {
                    const int g = b * CAP_ + pos;
                    cs[g] = score;
                    clab[g] = c;
                    corig[g] = pi * (CC_ - 1) + (c - 1);
                    cpidx[g] = p;
                }
            }
        }
    }
}

// ---------------------------------------------------------------------------
// Kernel 2: per-candidate box regression (FP64 dot) + strict-fp32 decode.
// (unchanged — bit-exact)
// ---------------------------------------------------------------------------
__global__ __launch_bounds__(256) void decode_cand(
    const float* __restrict__ A, const float* __restrict__ Wb,
    const float* __restrict__ bb, const float* __restrict__ props,
    const int* __restrict__ cnt, const int* __restrict__ clab,
    const int* __restrict__ cpidx,
    float* __restrict__ cs, float* __restrict__ cx1, float* __restrict__ cy1,
    float* __restrict__ cx2, float* __restrict__ cy2)
{
    const int wid = (blockIdx.x * 256 + threadIdx.x) >> 6;
    const int lane = threadIdx.x & 63;
    const int b = wid / CAP_;
    const int pos = wid - b * CAP_;
    if (b >= BB_) return;
    const int n = min(cnt[b], CAP_);
    if (pos >= n) return;

    const int g = b * CAP_ + pos;
    const int p = cpidx[g];
    const int c = clab[g];

    const float* fr = A + (size_t)p * FF_;
    const float* wb0 = Wb + 4 * c;

    double a0 = 0.0, a1 = 0.0, a2 = 0.0, a3 = 0.0;
    for (int k = lane; k < FF_; k += 64) {
        const double f = (double)fr[k];
        const float4 wv = *reinterpret_cast<const float4*>(wb0 + (size_t)k * (CC_ * 4));
        a0 += f * (double)wv.x; a1 += f * (double)wv.y;
        a2 += f * (double)wv.z; a3 += f * (double)wv.w;
    }
#pragma unroll
    for (int off = 32; off > 0; off >>= 1) {
        a0 += __shfl_xor(a0, off);
        a1 += __shfl_xor(a1, off);
        a2 += __shfl_xor(a2, off);
        a3 += __shfl_xor(a3, off);
    }

    if (lane == 0) {
        const float dx = __fadd_rn((float)a0, bb[4 * c + 0]);
        const float dy = __fadd_rn((float)a1, bb[4 * c + 1]);
        const float clipf = (float)BBOX_CLIP_D;
        const float dw = fminf(__fadd_rn((float)a2, bb[4 * c + 2]), clipf);
        const float dh = fminf(__fadd_rn((float)a3, bb[4 * c + 3]), clipf);

        const float px1 = props[(size_t)p * 4 + 0];
        const float py1 = props[(size_t)p * 4 + 1];
        const float px2 = props[(size_t)p * 4 + 2];
        const float py2 = props[(size_t)p * 4 + 3];
        const float w = __fsub_rn(px2, px1);
        const float h = __fsub_rn(py2, py1);
        const float cx = __fadd_rn(px1, __fmul_rn(0.5f, w));
        const float cy = __fadd_rn(py1, __fmul_rn(0.5f, h));

        const float pcx = __fadd_rn(__fmul_rn(dx, w), cx);
        const float pcy = __fadd_rn(__fmul_rn(dy, h), cy);
        const float ew = (float)exp((double)dw);
        const float eh = (float)exp((double)dh);
        const float pw = __fmul_rn(ew, w);
        const float ph = __fmul_rn(eh, h);

        const float hw = __fmul_rn(0.5f, pw);
        const float hh = __fmul_rn(0.5f, ph);
        const float bx1 = fminf(fmaxf(__fsub_rn(pcx, hw), 0.f), IMG_W);
        const float by1 = fminf(fmaxf(__fsub_rn(pcy, hh), 0.f), IMG_H);
        const float bx2 = fminf(fmaxf(__fadd_rn(pcx, hw), 0.f), IMG_W);
        const float by2 = fminf(fmaxf(__fadd_rn(pcy, hh), 0.f), IMG_H);

        cx1[g] = bx1; cy1[g] = by1; cx2[g] = bx2; cy2[g] = by2;
        if (!(__fsub_rn(bx2, bx1) >= MIN_SZ && __fsub_rn(by2, by1) >= MIN_SZ)) {
            cs[g] = -INFINITY;
        }
    }
}

// ---------------------------------------------------------------------------
// Kernel 3: per-(image,class) greedy NMS — one wave per (b,c) pair.
// (unchanged — bit-exact)
// ---------------------------------------------------------------------------
__global__ __launch_bounds__(64) void nms_class(
    const float* __restrict__ c_x1, const float* __restrict__ c_y1,
    const float* __restrict__ c_x2, const float* __restrict__ c_y2,
    const float* __restrict__ c_s, const int* __restrict__ c_lab,
    const int* __restrict__ c_orig, const int* __restrict__ cnt,
    ull* __restrict__ skey, float* __restrict__ sx1v, float* __restrict__ sy1v,
    float* __restrict__ sx2v, float* __restrict__ sy2v,
    int* __restrict__ slabv, int* __restrict__ scnt)
{
    const int blk = blockIdx.x;
    const int b = blk / (CC_ - 1);
    const int c = 1 + (blk - b * (CC_ - 1));
    const int lane = threadIdx.x;

    __shared__ ull kk[CLS_CAP];
    __shared__ float x1s[CLS_CAP], y1s[CLS_CAP], x2s[CLS_CAP], y2s[CLS_CAP];

    const int n = min(cnt[b], CAP_);

    int mcnt = 0;
    for (int i0 = 0; i0 < n; i0 += 64) {
        const int i = i0 + lane;
        bool take = false;
        float s = 0.f; int so = 0; int g = 0;
        if (i < n) {
            g = b * CAP_ + i;
            if (c_lab[g] == c) {
                s = c_s[g];
                if (s > 0.f) { take = true; so = c_orig[g]; }
            }
        }
        const ull bal = __ballot(take);
        if (take) {
            const int pos = mcnt + __popcll(bal & ((1ull << lane) - 1ull));
            if (pos < CLS_CAP) {
                kk[pos] = ((ull)__float_as_uint(s) << 32) |
                          (unsigned int)(0x7FFFFFFF - so);
                x1s[pos] = c_x1[g]; y1s[pos] = c_y1[g];
                x2s[pos] = c_x2[g]; y2s[pos] = c_y2[g];
            }
        }
        mcnt += (int)__popcll(bal);
    }
    mcnt = min(mcnt, CLS_CAP);
    if (mcnt == 0) return;
    __syncthreads();

    while (true) {
        ull best = 0ull;
        for (int i = lane; i < mcnt; i += 64) best = (kk[i] > best) ? kk[i] : best;
#pragma unroll
        for (int off = 32; off > 0; off >>= 1) {
            const ull o = __shfl_xor(best, off);
            best = (o > best) ? o : best;
        }
        if (best == 0ull) break;

        int wsl = -1;
        for (int i = lane; i < mcnt; i += 64) if (kk[i] == best) wsl = i;
        const ull bal = __ballot(wsl >= 0);
        const int wlane = (int)__ffsll((long long)bal) - 1;
        wsl = __shfl(wsl, wlane);

        const float wx1 = x1s[wsl], wy1 = y1s[wsl];
        const float wx2 = x2s[wsl], wy2 = y2s[wsl];

        if (lane == 0) {
            const int sp = atomicAdd(&scnt[b], 1);
            if (sp < SURV_CAP) {
                const int sg = b * SURV_CAP + sp;
                skey[sg] = best;
                sx1v[sg] = wx1; sy1v[sg] = wy1;
                sx2v[sg] = wx2; sy2v[sg] = wy2;
                slabv[sg] = c;
            }
        }

        const float off = __fmul_rn((float)c, OFF_);
        const float ax1 = __fadd_rn(wx1, off), ay1 = __fadd_rn(wy1, off);
        const float ax2 = __fadd_rn(wx2, off), ay2 = __fadd_rn(wy2, off);
        const float a1 = __fmul_rn(__fsub_rn(ax2, ax1), __fsub_rn(ay2, ay1));
        for (int i = lane; i < mcnt; i += 64) {
            if (kk[i] == 0ull) continue;
            const float bx1 = __fadd_rn(x1s[i], off), by1 = __fadd_rn(y1s[i], off);
            const float bx2 = __fadd_rn(x2s[i], off), by2 = __fadd_rn(y2s[i], off);
            const float ix1 = fmaxf(ax1, bx1), iy1 = fmaxf(ay1, by1);
            const float ix2 = fminf(ax2, bx2), iy2 = fminf(ay2, by2);
            const float inter = __fmul_rn(fmaxf(__fsub_rn(ix2, ix1), 0.f),
                                          fmaxf(__fsub_rn(iy2, iy1), 0.f));
            const float a2 = __fmul_rn(__fsub_rn(bx2, bx1), __fsub_rn(by2, by1));
            const float den = __fadd_rn(__fsub_rn(__fadd_rn(a1, a2), inter), 1e-9f);
            const float iou = __fdiv_rn(inter, den);
            if (iou > NMS_TH) kk[i] = 0ull;
        }
        __syncthreads();
    }
}

// ---------------------------------------------------------------------------
// Kernel 4: per-image merge — bitonic sort survivors by key (desc), emit
// top-100 in order. (unchanged — bit-exact)
// ---------------------------------------------------------------------------
__global__ __launch_bounds__(256) void nms_merge(
    const ull* __restrict__ skey, const float* __restrict__ sx1v,
    const float* __restrict__ sy1v, const float* __restrict__ sx2v,
    const float* __restrict__ sy2v, const int* __restrict__ slabv,
    const int* __restrict__ scnt, float* __restrict__ out)
{
    const int b = blockIdx.x;
    const int t = threadIdx.x;

    __shared__ ull k_[SURV_CAP];
    __shared__ int id_[SURV_CAP];

    const int m = min(scnt[b], SURV_CAP);
    int N2 = 128;
    while (N2 < m) N2 <<= 1;

    for (int i = t; i < N2; i += 256) {
        k_[i] = (i < m) ? skey[b * SURV_CAP + i] : 0ull;
        id_[i] = i;
    }
    __syncthreads();

    for (int ksz = 2; ksz <= N2; ksz <<= 1) {
        for (int j = ksz >> 1; j > 0; j >>= 1) {
            for (int i = t; i < N2; i += 256) {
                const int ixj = i ^ j;
                if (ixj > i) {
                    const ull a = k_[i], cc = k_[ixj];
                    const bool desc = ((i & ksz) == 0);
                    if (desc ? (a < cc) : (a > cc)) {
                        k_[i] = cc; k_[ixj] = a;
                        const int tmp = id_[i]; id_[i] = id_[ixj]; id_[ixj] = tmp;
                    }
                }
            }
            __syncthreads();
        }
    }

    const int boxes_base = 0;
    const int scores_base = BB_ * DETS_ * 4;
    const int labels_base = BB_ * DETS_ * 5;

    for (int r = t; r < DETS_; r += 256) {
        const ull key = (r < N2) ? k_[r] : 0ull;
        float* bo = out + boxes_base + (size_t)(b * DETS_ + r) * 4;
        if (key != 0ull) {
            const int sg = b * SURV_CAP + id_[r];
            bo[0] = sx1v[sg]; bo[1] = sy1v[sg];
            bo[2] = sx2v[sg]; bo[3] = sy2v[sg];
            out[scores_base + b * DETS_ + r] = __uint_as_float((unsigned)(key >> 32));
            out[labels_base + b * DETS_ + r] = (float)slabv[sg];
        } else {
            bo[0] = 0.f; bo[1] = 0.f; bo[2] = 0.f; bo[3] = 0.f;
            out[scores_base + b * DETS_ + r] = 0.f;
            out[labels_base + b * DETS_ + r] = 0.f;
        }
    }
}

// ---------------------------------------------------------------------------
extern "C" void kernel_launch(void* const* d_in, const int* in_sizes, int n_in,
                              void* d_out, int out_size, void* d_ws, size_t ws_size,
                              hipStream_t stream)
{
    const float* feat  = (const float*)d_in[0];
    const float* Wc    = (const float*)d_in[1];
    const float* bc    = (const float*)d_in[2];
    const float* Wb    = (const float*)d_in[3];
    const float* bb    = (const float*)d_in[4];
    const float* props = (const float*)d_in[5];
    for (int i = 0; i < n_in; ++i) {
        const float* q = (const float*)d_in[i];
        switch (in_sizes[i]) {
            case 16384000: feat  = q; break;  // [16000,1024]
            case 93184:    Wc    = q; break;  // [1024,91]
            case 91:       bc    = q; break;
            case 372736:   Wb    = q; break;  // [1024,364]
            case 364:      bb    = q; break;
            case 64000:    props = q; break;  // [16,1000,4]
        }
    }
    float* out = (float*)d_out;

    char* ws = (char*)d_ws;
    int*   cnt   = (int*)ws;            // 16 ints
    int*   scnt  = (int*)(ws + 64);     // 16 ints
    float* cs    = (float*)(ws + 256);
    int*   clab  = (int*)(cs + CAND_MAX);
    int*   corig = clab + CAND_MAX;
    int*   cpidx = corig + CAND_MAX;
    float* cx1   = (float*)(cpidx + CAND_MAX);
    float* cy1   = cx1 + CAND_MAX;
    float* cx2   = cy1 + CAND_MAX;
    float* cy2   = cx2 + CAND_MAX;
    ull*   skey  = (ull*)(cy2 + CAND_MAX);
    float* sx1v  = (float*)(skey + (size_t)BB_ * SURV_CAP);
    float* sy1v  = sx1v + (size_t)BB_ * SURV_CAP;
    float* sx2v  = sy1v + (size_t)BB_ * SURV_CAP;
    float* sy2v  = sx2v + (size_t)BB_ * SURV_CAP;
    int*   slabv = (int*)(sy2v + (size_t)BB_ * SURV_CAP);
    double* Wcd  = (double*)(slabv + (size_t)BB_ * SURV_CAP);  // 16B-aligned

    hipMemsetAsync(ws, 0, 256, stream);   // zero cnt + scnt

    wc_to_double<<<(FF_ * 96 + 255) / 256, 256, 0, stream>>>(Wc, Wcd);

    logits_cand<<<PP_ * BB_ / 16, 128, 0, stream>>>(feat, Wcd, bc,
        cs, clab, corig, cpidx, cnt);

    decode_cand<<<CAND_MAX / 4, 256, 0, stream>>>(feat, Wb, bb, props,
        cnt, clab, cpidx, cs, cx1, cy1, cx2, cy2);

    nms_class<<<BB_ * (CC_ - 1), 64, 0, stream>>>(
        cx1, cy1, cx2, cy2, cs, clab, corig, cnt,
        skey, sx1v, sy1v, sx2v, sy2v, slabv, scnt);

    nms_merge<<<BB_, 256, 0, stream>>>(
        skey, sx1v, sy1v, sx2v, sy2v, slabv, scnt, out);
}

// Round 9
// 291.637 us; speedup vs baseline: 1.3426x; 1.3426x over previous
//
#include <hip/hip_runtime.h>
#include <hip/hip_bf16.h>
#include <math.h>

typedef unsigned long long ull;

// Problem constants
#define BB_ 16          // images
#define PP_ 1000        // proposals per image
#define CC_ 91          // classes incl background
#define FF_ 1024        // feature dim
#define DETS_ 100
#define CAP_ 2048       // candidate capacity per image (measured ~320)
#define CAND_MAX (BB_ * CAP_)
#define SURV_CAP 2048   // NMS-survivor capacity per image
#define CLS_CAP 256     // per-(image,class) candidate capacity
#define IMG_W 800.0f
#define IMG_H 800.0f
#define OFF_ 802.0f     // max(H,W)+2
#define SCORE_TH 0.05f
#define NMS_TH 0.5f
#define MIN_SZ 0.01f
#define BBOX_CLIP_D 4.135166556742356   // log(1000/16)
#define WCD_ROWS 1028   // 1024 + prefetch-tail pad (rows 1024..1027 never consumed)

// ---------------------------------------------------------------------------
// Kernel 0: Wc (fp32 [1024][91]) -> Wcd (fp64 [1024][96], zero-padded cols).
// ---------------------------------------------------------------------------
__global__ __launch_bounds__(256) void wc_to_double(
    const float* __restrict__ Wc, double* __restrict__ Wcd)
{
    const int idx = blockIdx.x * 256 + threadIdx.x;
    if (idx >= FF_ * 96) return;
    const int k = idx / 96, c = idx - k * 96;
    Wcd[idx] = (c < CC_) ? (double)Wc[(size_t)k * CC_ + c] : 0.0;
}

// ---------------------------------------------------------------------------
// Kernel 1: logits GEMM, FP64 accumulation. ONE WAVE per block, 16 rows x
// 96 cols, per-lane 4x6. B read directly from fp64 Wcd (L2-resident) via a
// 4-slot depth-3 register pipeline (no converts, no LDS for B). A staged in
// 1.25KB LDS as float (4 cvt per k-iter). Single-wave ILP saturates the
// fp64 pipe; per-output K-accumulation strictly sequential -> identical
// logit bits to the passing R4-R8 kernels.
// ---------------------------------------------------------------------------
__global__ __launch_bounds__(64) void logits_cand(
    const float* __restrict__ A, const double* __restrict__ Wcd,
    const float* __restrict__ bc,
    float* __restrict__ cs, int* __restrict__ clab,
    int* __restrict__ corig, int* __restrict__ cpidx,
    int* __restrict__ cnt)
{
    __shared__ union __align__(16) SM {
        float Af[16][20];    // [k][row], stride 80B -> aligned b128, 2-way max
        float Ssc[16][97];   // logits tile (phase 2)
    } sm;

    const int lane = threadIdx.x;
    const int row0 = blockIdx.x * 16;
    const int cg = lane & 15;        // 16 col-groups x 6 cols = 96
    const int rg = lane >> 4;        // 4 row-groups x 4 rows = 16
    const int c0 = cg * 6;
    const int r0 = rg * 4;

    // A staging map: lane loads float4 of row (lane&15), k-quad (lane>>4)*4
    const int arow = lane & 15;
    const int akq  = (lane >> 4) * 4;

    double acc[4][6];
#pragma unroll
    for (int i = 0; i < 4; ++i)
#pragma unroll
        for (int j = 0; j < 6; ++j) acc[i][j] = 0.0;

    const double* bW = Wcd + c0;

    // B register pipeline: 4 slots x 3 double2, depth-3 prefetch.
    double2 bs0[3], bs1[3], bs2[3], bs3[3];
    {
        const double* p0 = bW;
        const double* p1 = bW + 96;
        const double* p2 = bW + 192;
        bs0[0] = *(const double2*)(p0);     bs0[1] = *(const double2*)(p0 + 2); bs0[2] = *(const double2*)(p0 + 4);
        bs1[0] = *(const double2*)(p1);     bs1[1] = *(const double2*)(p1 + 2); bs1[2] = *(const double2*)(p1 + 4);
        bs2[0] = *(const double2*)(p2);     bs2[1] = *(const double2*)(p2 + 2); bs2[2] = *(const double2*)(p2 + 4);
    }

    // A prefetch (k0 = 0)
    float4 avP = *(const float4*)(A + (size_t)(row0 + arow) * FF_ + akq);

    for (int k0 = 0; k0 < FF_; k0 += 16) {
        // stage current A tile
        sm.Af[akq + 0][arow] = avP.x;
        sm.Af[akq + 1][arow] = avP.y;
        sm.Af[akq + 2][arow] = avP.z;
        sm.Af[akq + 3][arow] = avP.w;
        // prefetch next A tile (clamped re-read on last step; unused)
        {
            const int kn = (k0 + 16 < FF_) ? (k0 + 16) : k0;
            avP = *(const float4*)(A + (size_t)(row0 + arow) * FF_ + kn + akq);
        }
        __syncthreads();   // single-wave: compiles to waitcnt only

        const double* bbase = bW + (size_t)k0 * 96;

#pragma unroll
        for (int j = 0; j < 16; ++j) {
            // prefetch gk = k0+j+3 into slot (j+3)&3 (Wcd padded: no guard)
            {
                const double* p = bbase + (size_t)(j + 3) * 96;
                double2 q0 = *(const double2*)(p);
                double2 q1 = *(const double2*)(p + 2);
                double2 q2 = *(const double2*)(p + 4);
                switch ((j + 3) & 3) {
                    case 0: bs0[0] = q0; bs0[1] = q1; bs0[2] = q2; break;
                    case 1: bs1[0] = q0; bs1[1] = q1; bs1[2] = q2; break;
                    case 2: bs2[0] = q0; bs2[1] = q1; bs2[2] = q2; break;
                    default: bs3[0] = q0; bs3[1] = q1; bs3[2] = q2; break;
                }
            }
            double2 q0, q1, q2;
            switch (j & 3) {
                case 0: q0 = bs0[0]; q1 = bs0[1]; q2 = bs0[2]; break;
                case 1: q0 = bs1[0]; q1 = bs1[1]; q2 = bs1[2]; break;
                case 2: q0 = bs2[0]; q1 = bs2[1]; q2 = bs2[2]; break;
                default: q0 = bs3[0]; q1 = bs3[1]; q2 = bs3[2]; break;
            }
            const float4 af = *(const float4*)(&sm.Af[j][r0]);
            const double a0 = (double)af.x, a1 = (double)af.y;
            const double a2 = (double)af.z, a3 = (double)af.w;

            acc[0][0] += a0 * q0.x; acc[0][1] += a0 * q0.y;
            acc[0][2] += a0 * q1.x; acc[0][3] += a0 * q1.y;
            acc[0][4] += a0 * q2.x; acc[0][5] += a0 * q2.y;
            acc[1][0] += a1 * q0.x; acc[1][1] += a1 * q0.y;
            acc[1][2] += a1 * q1.x; acc[1][3] += a1 * q1.y;
            acc[1][4] += a1 * q2.x; acc[1][5] += a1 * q2.y;
            acc[2][0] += a2 * q0.x; acc[2][1] += a2 * q0.y;
            acc[2][2] += a2 * q1.x; acc[2][3] += a2 * q1.y;
            acc[2][4] += a2 * q2.x; acc[2][5] += a2 * q2.y;
            acc[3][0] += a3 * q0.x; acc[3][1] += a3 * q0.y;
            acc[3][2] += a3 * q1.x; acc[3][3] += a3 * q1.y;
            acc[3][4] += a3 * q2.x; acc[3][5] += a3 * q2.y;
        }
        __syncthreads();
    }

    // fp32 logits (+bias) into LDS
#pragma unroll
    for (int i = 0; i < 4; ++i)
#pragma unroll
        for (int j = 0; j < 6; ++j) {
            const int c = c0 + j;
            if (c < CC_) {
                const float lf = (float)acc[i][j];
                sm.Ssc[r0 + i][c] = __fadd_rn(lf, bc[c]);
            }
        }
    __syncthreads();

    // softmax: 4 workers per row (row = lane&15, w = lane>>4), stride-4 cols
    {
        const int row = lane & 15;
        const int w = lane >> 4;
        const int p = row0 + row;
        const int b = p / PP_;
        const int pi = p - b * PP_;

        float m = -INFINITY;
        for (int c = w; c < CC_; c += 4) m = fmaxf(m, sm.Ssc[row][c]);
        m = fmaxf(m, __shfl_xor(m, 16));
        m = fmaxf(m, __shfl_xor(m, 32));

        double denom = 0.0;
        for (int c = w; c < CC_; c += 4)
            denom += exp((double)sm.Ssc[row][c] - (double)m);
        denom += __shfl_xor(denom, 16);
        denom += __shfl_xor(denom, 32);

        for (int c = (w == 0 ? 4 : w); c < CC_; c += 4) {
            const double sd = exp((double)sm.Ssc[row][c] - (double)m) / denom;
            const float score = (float)sd;
            if (score > SCORE_TH) {
                const int pos = atomicAdd(&cnt[b], 1);
                if (pos < CAP_) {
                    const int g = b * CAP_ + pos;
                    cs[g] = score;
                    clab[g] = c;
                    corig[g] = pi * (CC_ - 1) + (c - 1);
                    cpidx[g] = p;
                }
            }
        }
    }
}

// ---------------------------------------------------------------------------
// Kernel 2: per-candidate box regression (FP64 dot) + strict-fp32 decode.
// (unchanged — bit-exact)
// ---------------------------------------------------------------------------
__global__ __launch_bounds__(256) void decode_cand(
    const float* __restrict__ A, const float* __restrict__ Wb,
    const float* __restrict__ bb, const float* __restrict__ props,
    const int* __restrict__ cnt, const int* __restrict__ clab,
    const int* __restrict__ cpidx,
    float* __restrict__ cs, float* __restrict__ cx1, float* __restrict__ cy1,
    float* __restrict__ cx2, float* __restrict__ cy2)
{
    const int wid = (blockIdx.x * 256 + threadIdx.x) >> 6;
    const int lane = threadIdx.x & 63;
    const int b = wid / CAP_;
    const int pos = wid - b * CAP_;
    if (b >= BB_) return;
    const int n = min(cnt[b], CAP_);
    if (pos >= n) return;

    const int g = b * CAP_ + pos;
    const int p = cpidx[g];
    const int c = clab[g];

    const float* fr = A + (size_t)p * FF_;
    const float* wb0 = Wb + 4 * c;

    double a0 = 0.0, a1 = 0.0, a2 = 0.0, a3 = 0.0;
    for (int k = lane; k < FF_; k += 64) {
        const double f = (double)fr[k];
        const float4 wv = *reinterpret_cast<const float4*>(wb0 + (size_t)k * (CC_ * 4));
        a0 += f * (double)wv.x; a1 += f * (double)wv.y;
        a2 += f * (double)wv.z; a3 += f * (double)wv.w;
    }
#pragma unroll
    for (int off = 32; off > 0; off >>= 1) {
        a0 += __shfl_xor(a0, off);
        a1 += __shfl_xor(a1, off);
        a2 += __shfl_xor(a2, off);
        a3 += __shfl_xor(a3, off);
    }

    if (lane == 0) {
        const float dx = __fadd_rn((float)a0, bb[4 * c + 0]);
        const float dy = __fadd_rn((float)a1, bb[4 * c + 1]);
        const float clipf = (float)BBOX_CLIP_D;
        const float dw = fminf(__fadd_rn((float)a2, bb[4 * c + 2]), clipf);
        const float dh = fminf(__fadd_rn((float)a3, bb[4 * c + 3]), clipf);

        const float px1 = props[(size_t)p * 4 + 0];
        const float py1 = props[(size_t)p * 4 + 1];
        const float px2 = props[(size_t)p * 4 + 2];
        const float py2 = props[(size_t)p * 4 + 3];
        const float w = __fsub_rn(px2, px1);
        const float h = __fsub_rn(py2, py1);
        const float cx = __fadd_rn(px1, __fmul_rn(0.5f, w));
        const float cy = __fadd_rn(py1, __fmul_rn(0.5f, h));

        const float pcx = __fadd_rn(__fmul_rn(dx, w), cx);
        const float pcy = __fadd_rn(__fmul_rn(dy, h), cy);
        const float ew = (float)exp((double)dw);
        const float eh = (float)exp((double)dh);
        const float pw = __fmul_rn(ew, w);
        const float ph = __fmul_rn(eh, h);

        const float hw = __fmul_rn(0.5f, pw);
        const float hh = __fmul_rn(0.5f, ph);
        const float bx1 = fminf(fmaxf(__fsub_rn(pcx, hw), 0.f), IMG_W);
        const float by1 = fminf(fmaxf(__fsub_rn(pcy, hh), 0.f), IMG_H);
        const float bx2 = fminf(fmaxf(__fadd_rn(pcx, hw), 0.f), IMG_W);
        const float by2 = fminf(fmaxf(__fadd_rn(pcy, hh), 0.f), IMG_H);

        cx1[g] = bx1; cy1[g] = by1; cx2[g] = bx2; cy2[g] = by2;
        if (!(__fsub_rn(bx2, bx1) >= MIN_SZ && __fsub_rn(by2, by1) >= MIN_SZ)) {
            cs[g] = -INFINITY;
        }
    }
}

// ---------------------------------------------------------------------------
// Kernel 3: per-(image,class) greedy NMS — one wave per (b,c) pair.
// (unchanged — bit-exact)
// ---------------------------------------------------------------------------
__global__ __launch_bounds__(64) void nms_class(
    const float* __restrict__ c_x1, const float* __restrict__ c_y1,
    const float* __restrict__ c_x2, const float* __restrict__ c_y2,
    const float* __restrict__ c_s, const int* __restrict__ c_lab,
    const int* __restrict__ c_orig, const int* __restrict__ cnt,
    ull* __restrict__ skey, float* __restrict__ sx1v, float* __restrict__ sy1v,
    float* __restrict__ sx2v, float* __restrict__ sy2v,
    int* __restrict__ slabv, int* __restrict__ scnt)
{
    const int blk = blockIdx.x;
    const int b = blk / (CC_ - 1);
    const int c = 1 + (blk - b * (CC_ - 1));
    const int lane = threadIdx.x;

    __shared__ ull kk[CLS_CAP];
    __shared__ float x1s[CLS_CAP], y1s[CLS_CAP], x2s[CLS_CAP], y2s[CLS_CAP];

    const int n = min(cnt[b], CAP_);

    int mcnt = 0;
    for (int i0 = 0; i0 < n; i0 += 64) {
        const int i = i0 + lane;
        bool take = false;
        float s = 0.f; int so = 0; int g = 0;
        if (i < n) {
            g = b * CAP_ + i;
            if (c_lab[g] == c) {
                s = c_s[g];
                if (s > 0.f) { take = true; so = c_orig[g]; }
            }
        }
        const ull bal = __ballot(take);
        if (take) {
            const int pos = mcnt + __popcll(bal & ((1ull << lane) - 1ull));
            if (pos < CLS_CAP) {
                kk[pos] = ((ull)__float_as_uint(s) << 32) |
                          (unsigned int)(0x7FFFFFFF - so);
                x1s[pos] = c_x1[g]; y1s[pos] = c_y1[g];
                x2s[pos] = c_x2[g]; y2s[pos] = c_y2[g];
            }
        }
        mcnt += (int)__popcll(bal);
    }
    mcnt = min(mcnt, CLS_CAP);
    if (mcnt == 0) return;
    __syncthreads();

    while (true) {
        ull best = 0ull;
        for (int i = lane; i < mcnt; i += 64) best = (kk[i] > best) ? kk[i] : best;
#pragma unroll
        for (int off = 32; off > 0; off >>= 1) {
            const ull o = __shfl_xor(best, off);
            best = (o > best) ? o : best;
        }
        if (best == 0ull) break;

        int wsl = -1;
        for (int i = lane; i < mcnt; i += 64) if (kk[i] == best) wsl = i;
        const ull bal = __ballot(wsl >= 0);
        const int wlane = (int)__ffsll((long long)bal) - 1;
        wsl = __shfl(wsl, wlane);

        const float wx1 = x1s[wsl], wy1 = y1s[wsl];
        const float wx2 = x2s[wsl], wy2 = y2s[wsl];

        if (lane == 0) {
            const int sp = atomicAdd(&scnt[b], 1);
            if (sp < SURV_CAP) {
                const int sg = b * SURV_CAP + sp;
                skey[sg] = best;
                sx1v[sg] = wx1; sy1v[sg] = wy1;
                sx2v[sg] = wx2; sy2v[sg] = wy2;
                slabv[sg] = c;
            }
        }

        const float off = __fmul_rn((float)c, OFF_);
        const float ax1 = __fadd_rn(wx1, off), ay1 = __fadd_rn(wy1, off);
        const float ax2 = __fadd_rn(wx2, off), ay2 = __fadd_rn(wy2, off);
        const float a1 = __fmul_rn(__fsub_rn(ax2, ax1), __fsub_rn(ay2, ay1));
        for (int i = lane; i < mcnt; i += 64) {
            if (kk[i] == 0ull) continue;
            const float bx1 = __fadd_rn(x1s[i], off), by1 = __fadd_rn(y1s[i], off);
            const float bx2 = __fadd_rn(x2s[i], off), by2 = __fadd_rn(y2s[i], off);
            const float ix1 = fmaxf(ax1, bx1), iy1 = fmaxf(ay1, by1);
            const float ix2 = fminf(ax2, bx2), iy2 = fminf(ay2, by2);
            const float inter = __fmul_rn(fmaxf(__fsub_rn(ix2, ix1), 0.f),
                                          fmaxf(__fsub_rn(iy2, iy1), 0.f));
            const float a2 = __fmul_rn(__fsub_rn(bx2, bx1), __fsub_rn(by2, by1));
            const float den = __fadd_rn(__fsub_rn(__fadd_rn(a1, a2), inter), 1e-9f);
            const float iou = __fdiv_rn(inter, den);
            if (iou > NMS_TH) kk[i] = 0ull;
        }
        __syncthreads();
    }
}

// ---------------------------------------------------------------------------
// Kernel 4: per-image merge — bitonic sort survivors by key (desc), emit
// top-100 in order. (unchanged — bit-exact)
// ---------------------------------------------------------------------------
__global__ __launch_bounds__(256) void nms_merge(
    const ull* __restrict__ skey, const float* __restrict__ sx1v,
    const float* __restrict__ sy1v, const float* __restrict__ sx2v,
    const float* __restrict__ sy2v, const int* __restrict__ slabv,
    const int* __restrict__ scnt, float* __restrict__ out)
{
    const int b = blockIdx.x;
    const int t = threadIdx.x;

    __shared__ ull k_[SURV_CAP];
    __shared__ int id_[SURV_CAP];

    const int m = min(scnt[b], SURV_CAP);
    int N2 = 128;
    while (N2 < m) N2 <<= 1;

    for (int i = t; i < N2; i += 256) {
        k_[i] = (i < m) ? skey[b * SURV_CAP + i] : 0ull;
        id_[i] = i;
    }
    __syncthreads();

    for (int ksz = 2; ksz <= N2; ksz <<= 1) {
        for (int j = ksz >> 1; j > 0; j >>= 1) {
            for (int i = t; i < N2; i += 256) {
                const int ixj = i ^ j;
                if (ixj > i) {
                    const ull a = k_[i], cc = k_[ixj];
                    const bool desc = ((i & ksz) == 0);
                    if (desc ? (a < cc) : (a > cc)) {
                        k_[i] = cc; k_[ixj] = a;
                        const int tmp = id_[i]; id_[i] = id_[ixj]; id_[ixj] = tmp;
                    }
                }
            }
            __syncthreads();
        }
    }

    const int boxes_base = 0;
    const int scores_base = BB_ * DETS_ * 4;
    const int labels_base = BB_ * DETS_ * 5;

    for (int r = t; r < DETS_; r += 256) {
        const ull key = (r < N2) ? k_[r] : 0ull;
        float* bo = out + boxes_base + (size_t)(b * DETS_ + r) * 4;
        if (key != 0ull) {
            const int sg = b * SURV_CAP + id_[r];
            bo[0] = sx1v[sg]; bo[1] = sy1v[sg];
            bo[2] = sx2v[sg]; bo[3] = sy2v[sg];
            out[scores_base + b * DETS_ + r] = __uint_as_float((unsigned)(key >> 32));
            out[labels_base + b * DETS_ + r] = (float)slabv[sg];
        } else {
            bo[0] = 0.f; bo[1] = 0.f; bo[2] = 0.f; bo[3] = 0.f;
            out[scores_base + b * DETS_ + r] = 0.f;
            out[labels_base + b * DETS_ + r] = 0.f;
        }
    }
}

// ---------------------------------------------------------------------------
extern "C" void kernel_launch(void* const* d_in, const int* in_sizes, int n_in,
                              void* d_out, int out_size, void* d_ws, size_t ws_size,
                              hipStream_t stream)
{
    const float* feat  = (const float*)d_in[0];
    const float* Wc    = (const float*)d_in[1];
    const float* bc    = (const float*)d_in[2];
    const float* Wb    = (const float*)d_in[3];
    const float* bb    = (const float*)d_in[4];
    const float* props = (const float*)d_in[5];
    for (int i = 0; i < n_in; ++i) {
        const float* q = (const float*)d_in[i];
        switch (in_sizes[i]) {
            case 16384000: feat  = q; break;  // [16000,1024]
            case 93184:    Wc    = q; break;  // [1024,91]
            case 91:       bc    = q; break;
            case 372736:   Wb    = q; break;  // [1024,364]
            case 364:      bb    = q; break;
            case 64000:    props = q; break;  // [16,1000,4]
        }
    }
    float* out = (float*)d_out;

    char* ws = (char*)d_ws;
    int*   cnt   = (int*)ws;            // 16 ints
    int*   scnt  = (int*)(ws + 64);     // 16 ints
    float* cs    = (float*)(ws + 256);
    int*   clab  = (int*)(cs + CAND_MAX);
    int*   corig = clab + CAND_MAX;
    int*   cpidx = corig + CAND_MAX;
    float* cx1   = (float*)(cpidx + CAND_MAX);
    float* cy1   = cx1 + CAND_MAX;
    float* cx2   = cy1 + CAND_MAX;
    float* cy2   = cx2 + CAND_MAX;
    ull*   skey  = (ull*)(cy2 + CAND_MAX);
    float* sx1v  = (float*)(skey + (size_t)BB_ * SURV_CAP);
    float* sy1v  = sx1v + (size_t)BB_ * SURV_CAP;
    float* sx2v  = sy1v + (size_t)BB_ * SURV_CAP;
    float* sy2v  = sx2v + (size_t)BB_ * SURV_CAP;
    int*   slabv = (int*)(sy2v + (size_t)BB_ * SURV_CAP);
    double* Wcd  = (double*)(slabv + (size_t)BB_ * SURV_CAP);  // 16B-aligned
    // Wcd occupies WCD_ROWS*96 doubles (rows >=1024 are prefetch pad)

    hipMemsetAsync(ws, 0, 256, stream);   // zero cnt + scnt

    wc_to_double<<<(FF_ * 96 + 255) / 256, 256, 0, stream>>>(Wc, Wcd);

    logits_cand<<<PP_ * BB_ / 16, 64, 0, stream>>>(feat, Wcd, bc,
        cs, clab, corig, cpidx, cnt);

    decode_cand<<<CAND_MAX / 4, 256, 0, stream>>>(feat, Wb, bb, props,
        cnt, clab, cpidx, cs, cx1, cy1, cx2, cy2);

    nms_class<<<BB_ * (CC_ - 1), 64, 0, stream>>>(
        cx1, cy1, cx2, cy2, cs, clab, corig, cnt,
        skey, sx1v, sy1v, sx2v, sy2v, slabv, scnt);

    nms_merge<<<BB_, 256, 0, stream>>>(
        skey, sx1v, sy1v, sx2v, sy2v, slabv, scnt, out);
}